// Round 5
// baseline (129.948 us; speedup 1.0000x reference)
//
#include <hip/hip_runtime.h>
#include <hip/hip_bf16.h>

#define HH 1024
#define LL 512
#define NT 16              // 512/32 row-tiles
#define NTRI 136           // NT*(NT+1)/2 triangular tiles

typedef __attribute__((ext_vector_type(8))) short bf16x8;
typedef __attribute__((ext_vector_type(4))) float f32x4;
typedef __attribute__((ext_vector_type(2))) float f32x2;

static constexpr float C_EXP = 2.8853900817779268f; // 2*log2(e)

// pack 8 fp32 -> 8 bf16 (RNE) as uint4
static __device__ __forceinline__ uint4 pack8(float4 a, float4 b) {
    union { uint4 u; __hip_bfloat162 h[4]; } r;
    r.h[0] = __float22bfloat162_rn(make_float2(a.x, a.y));
    r.h[1] = __float22bfloat162_rn(make_float2(a.z, a.w));
    r.h[2] = __float22bfloat162_rn(make_float2(b.x, b.y));
    r.h[3] = __float22bfloat162_rn(make_float2(b.z, b.w));
    return r.u;
}

// ---------------------------------------------------------------------------
// Kernel 1: bf16 MFMA projection, 64m x 32n tiles, grid 512 (2 blocks/CU
// resident = 2x latency hiding vs the original grid-256 64x64 form).
//   n < 1024:  Ea[m][n] = exp2(C*(acc+b1[n]));  else Eb[m][n-1024] = exp2(C*acc)
// ---------------------------------------------------------------------------
__global__ __launch_bounds__(256, 4) void proj_mfma_kernel(
    const float* __restrict__ lm, const float* __restrict__ W1,
    const float* __restrict__ b1, float* __restrict__ Ea, float* __restrict__ Eb)
{
    __shared__ ushort As[64][136];  // 136 us = 68 dw = 4 mod 32 banks: <=2-way, free
    __shared__ ushort Bs[32][136];

    const int tid  = threadIdx.x;
    const int lane = tid & 63;
    const int w    = tid >> 6;
    const int b    = blockIdx.x;          // 0..511
    const int xcd  = b & 7;
    const int idx  = b >> 3;              // 0..63
    const int nbase = (xcd * 8 + (idx & 7)) * 32;   // 0..2047 (32-wide n-tile)
    const int mbase = (idx >> 3) * 64;              // 0..448
    const int wm   = w * 16;
    const int sel  = nbase >> 10;         // block-uniform: Wa(0)/Wb(1)
    const int nrow = nbase & 1023;

    const int frow = lane & 15;
    const int q8   = (lane >> 4) * 8;

    f32x4 acc[2] = {};

    for (int kb = 0; kb < HH; kb += 128) {
        __syncthreads();
        {   // stage A (64x128 -> 1024 chunks) + B (32x128 -> 512 chunks), 6/thread
            int p = tid;
#pragma unroll
            for (int it = 0; it < 4; ++it, p += 256) {      // A chunks
                const int row = p >> 4, c8 = (p & 15) * 8;
                const float* pa = &lm[(mbase + row) * HH + kb + c8];
                *(uint4*)&As[row][c8] = pack8(*(const float4*)pa, *(const float4*)(pa + 4));
            }
            int q = tid;
#pragma unroll
            for (int it = 0; it < 2; ++it, q += 256) {      // B chunks
                const int row = q >> 4, c8 = (q & 15) * 8;
                const float* pw = &W1[(nrow + row) * 2048 + sel * 1024 + kb + c8];
                *(uint4*)&Bs[row][c8] = pack8(*(const float4*)pw, *(const float4*)(pw + 4));
            }
        }
        __syncthreads();

#pragma unroll
        for (int s = 0; s < 4; ++s) {
            const bf16x8 a = *(const bf16x8*)&As[wm + frow][s * 32 + q8];
#pragma unroll
            for (int nf = 0; nf < 2; ++nf) {
                const bf16x8 bb = *(const bf16x8*)&Bs[nf * 16 + frow][s * 32 + q8];
                acc[nf] = __builtin_amdgcn_mfma_f32_16x16x32_bf16(a, bb, acc[nf], 0, 0, 0);
            }
        }
    }

    // D mapping: col=lane&15 (n), row=(lane>>4)*4+reg (m)
    const int col = lane & 15;
    const int rq  = (lane >> 4) * 4;
    const int m0  = mbase + wm + rq;
    const bool isA = sel == 0;            // block-uniform
#pragma unroll
    for (int nf = 0; nf < 2; ++nf) {
        const int nn = (nrow + nf * 16 + col);
        if (isA) {
            const float bb = b1[nn];
#pragma unroll
            for (int r = 0; r < 4; ++r)
                Ea[(m0 + r) * HH + nn] = __builtin_amdgcn_exp2f(C_EXP * (acc[nf][r] + bb));
        } else {
#pragma unroll
            for (int r = 0; r < 4; ++r)
                Eb[(m0 + r) * HH + nn] = __builtin_amdgcn_exp2f(C_EXP * acc[nf][r]);
        }
    }
}

// ---------------------------------------------------------------------------
// Kernel 2: triangular pairwise contraction — ROUND-0 SHELL (32x32 tile, 2x2
// per thread, proven staging + xor swizzle + occupancy), NEW INNER MATH:
// pure scalar, 38 issue-slots per (ii,jj,4h) group = 4.75/ordered element
// (vs 9.5 measured for the f32x2 form). Batched reciprocal: one v_rcp per
// 4 denominator-products; q_k = n_k * m_partner * R-recovery.
// No f32x2 in the hot loop (gfx950 v_pk_f32 gives no issue-rate gain and
// costs shuffle/mov marshaling). Named scalar accumulators (no dyn-index).
// ---------------------------------------------------------------------------
__global__ __launch_bounds__(256, 4) void pair_kernel(
    const float* __restrict__ Ea, const float* __restrict__ Eb,
    const float* __restrict__ W2, float* __restrict__ pbuf, int slice)
{
    // [0]=Ea[j] (xor), [1]=Ea[i] (plain), [2]=Eb[i] (plain), [3]=Eb[j] (xor)
    __shared__ float tl[4][32][64];   // 32768 B exactly

    const int tid = threadIdx.x;
    const int tx  = tid & 15;
    const int ty  = tid >> 4;         // 0..15

    int tt = blockIdx.x, bi = 0, rem = NT;          // triangular decode
    while (tt >= rem) { tt -= rem; --rem; ++bi; }
    const int bj    = bi + tt;
    const int ibase = bi * 32;
    const int jbase = bj * 32;
    const int k0    = blockIdx.y * slice;

    // named scalar accumulators: acc<ii><jj>_<channel>
    float a00_0 = 0.f, a00_1 = 0.f, a01_0 = 0.f, a01_1 = 0.f;
    float a10_0 = 0.f, a10_1 = 0.f, a11_0 = 0.f, a11_1 = 0.f;

    for (int kb = 0; kb < slice; kb += 64) {
        if (kb) __syncthreads();
        {   // stage 4 tiles x 32 rows x 64 floats = 2048 float4, 8/thread
            int p = tid;
#pragma unroll
            for (int it = 0; it < 8; ++it, p += 256) {
                const int tile = p >> 9;             // compile-time per it
                const int row  = (p >> 4) & 31;
                const int c4   = p & 15;
                float4 v;
                if      (tile == 0) v = *(const float4*)&Ea[(jbase + row) * HH + k0 + kb + c4 * 4];
                else if (tile == 1) v = *(const float4*)&Ea[(ibase + row) * HH + k0 + kb + c4 * 4];
                else if (tile == 2) v = *(const float4*)&Eb[(ibase + row) * HH + k0 + kb + c4 * 4];
                else                v = *(const float4*)&Eb[(jbase + row) * HH + k0 + kb + c4 * 4];
                const int c4s = (tile == 0 || tile == 3) ? (c4 ^ (row & 15)) : c4;
                *(float4*)&tl[tile][row][c4s * 4] = v;
            }
        }
        __syncthreads();

#pragma unroll 2
        for (int h4 = 0; h4 < 16; ++h4) {
            const int sx = (h4 ^ tx) * 4;            // xor-swizzled column
            const float4 Aj0 = *(const float4*)&tl[0][tx][sx];
            const float4 Aj1 = *(const float4*)&tl[0][tx + 16][sx];
            const float4 Bj0 = *(const float4*)&tl[3][tx][sx];
            const float4 Bj1 = *(const float4*)&tl[3][tx + 16][sx];
            const float4 Ai0 = *(const float4*)&tl[1][ty][h4 * 4];
            const float4 Ai1 = *(const float4*)&tl[1][ty + 16][h4 * 4];
            const float4 Bi0 = *(const float4*)&tl[2][ty][h4 * 4];
            const float4 Bi1 = *(const float4*)&tl[2][ty + 16][h4 * 4];
            const float4 w0q = *(const float4*)&W2[k0 + kb + h4 * 4];      // uniform
            const float4 w1q = *(const float4*)&W2[HH + k0 + kb + h4 * 4];

            // d = 1 + Eb_i*Ea_j ; e = 1 + Ea_i*Eb_j ; u = 1/d + 1/e = n/(d*e)
            // batch-rcp 4 m's: R = rcp(m0m1m2m3); 1/(m0m1)=R*t23; q_k = n_k*m_part*Rx
#define PAIR(AIv, BIv, AJv, BJv, A0, A1)                                        \
            {                                                                    \
                const float d0 = fmaf(BIv.x, AJv.x, 1.f);                        \
                const float d1 = fmaf(BIv.y, AJv.y, 1.f);                        \
                const float d2 = fmaf(BIv.z, AJv.z, 1.f);                        \
                const float d3 = fmaf(BIv.w, AJv.w, 1.f);                        \
                const float e0 = fmaf(AIv.x, BJv.x, 1.f);                        \
                const float e1 = fmaf(AIv.y, BJv.y, 1.f);                        \
                const float e2 = fmaf(AIv.z, BJv.z, 1.f);                        \
                const float e3 = fmaf(AIv.w, BJv.w, 1.f);                        \
                const float m0 = d0 * e0, m1 = d1 * e1;                          \
                const float m2 = d2 * e2, m3 = d3 * e3;                          \
                const float n0 = d0 + e0, n1 = d1 + e1;                          \
                const float n2 = d2 + e2, n3 = d3 + e3;                          \
                const float t01 = m0 * m1, t23 = m2 * m3;                        \
                const float R  = __builtin_amdgcn_rcpf(t01 * t23);               \
                const float Ra = R * t23, Rb = R * t01;                          \
                const float q0 = n0 * m1 * Ra, q1 = n1 * m0 * Ra;                \
                const float q2 = n2 * m3 * Rb, q3 = n3 * m2 * Rb;                \
                A0 = fmaf(q0, w0q.x, fmaf(q1, w0q.y,                             \
                     fmaf(q2, w0q.z, fmaf(q3, w0q.w, A0))));                     \
                A1 = fmaf(q0, w1q.x, fmaf(q1, w1q.y,                             \
                     fmaf(q2, w1q.z, fmaf(q3, w1q.w, A1))));                     \
            }
            PAIR(Ai0, Bi0, Aj0, Bj0, a00_0, a00_1)
            PAIR(Ai0, Bi0, Aj1, Bj1, a01_0, a01_1)
            PAIR(Ai1, Bi1, Aj0, Bj0, a10_0, a10_1)
            PAIR(Ai1, Bi1, Aj1, Bj1, a11_0, a11_1)
#undef PAIR
        }
    }

    float* pb = pbuf + ((size_t)blockIdx.y * NTRI + blockIdx.x) * 2048;
    {
        const int li0 = ty, li1 = ty + 16, lj0 = tx, lj1 = tx + 16;
        *(f32x2*)&pb[(li0 * 32 + lj0) * 2] = (f32x2){a00_0, a00_1};
        *(f32x2*)&pb[(li0 * 32 + lj1) * 2] = (f32x2){a01_0, a01_1};
        *(f32x2*)&pb[(li1 * 32 + lj0) * 2] = (f32x2){a10_0, a10_1};
        *(f32x2*)&pb[(li1 * 32 + lj1) * 2] = (f32x2){a11_0, a11_1};
    }
}

// ---------------------------------------------------------------------------
// Kernel 3: combine (round-0 proven form): out = wsum[c]+b2[c] - sum_z pbuf;
// scatter to (i,j) and (j,i). 1088 blocks, 2-way ILP on z.
// ---------------------------------------------------------------------------
__global__ __launch_bounds__(256) void combine_kernel(
    const float* __restrict__ pbuf, const float* __restrict__ W2,
    const float* __restrict__ b2, float* __restrict__ out, int nz)
{
    __shared__ float s_ws[2];

    const int tid = threadIdx.x;
    if (tid < 128) {
        const int c = tid >> 6, l = tid & 63;
        float s = 0.f;
#pragma unroll
        for (int q = 0; q < 4; ++q) {
            const float4 v = *(const float4*)&W2[c * HH + (l + q * 64) * 4];
            s += v.x + v.y + v.z + v.w;
        }
#pragma unroll
        for (int off = 32; off; off >>= 1) s += __shfl_down(s, off, 64);
        if (l == 0) s_ws[c] = s + b2[c];
    }
    __syncthreads();

    const int idx   = blockIdx.x * 256 + tid;   // 0 .. 136*2048-1
    const int t     = idx >> 11;                // block-uniform
    const int local = idx & 2047;
    int tt = t, bi = 0, rem = NT;
    while (tt >= rem) { tt -= rem; --rem; ++bi; }
    const int bj = bi + tt;

    float s0 = 0.f, s1 = 0.f;
    for (int z = 0; z < nz; z += 2) {   // nz is even
        s0 += pbuf[((size_t)z * NTRI + t) * 2048 + local];
        s1 += pbuf[((size_t)(z + 1) * NTRI + t) * 2048 + local];
    }
    const float s = s0 + s1;

    const int li = local >> 6;
    const int lj = (local >> 1) & 31;
    const int c  = local & 1;
    const float v = s_ws[c] - s;

    const int i = bi * 32 + li;
    const int j = bj * 32 + lj;
    out[(i * LL + j) * 2 + c] = v;
    out[(j * LL + i) * 2 + c] = v;   // diagonal tiles: same-value rewrite, benign
}

extern "C" void kernel_launch(void* const* d_in, const int* in_sizes, int n_in,
                              void* d_out, int out_size, void* d_ws, size_t ws_size,
                              hipStream_t stream)
{
    const float* lm = (const float*)d_in[0];
    const float* W1 = (const float*)d_in[1];
    const float* b1 = (const float*)d_in[2];
    const float* W2 = (const float*)d_in[3];
    const float* b2 = (const float*)d_in[4];
    float* out = (float*)d_out;

    char* ws = (char*)d_ws;
    float* Ea   = (float*)ws;                            // 2 MB
    float* Eb   = (float*)(ws + (2u << 20));             // 2 MB
    float* pbuf = (float*)(ws + (4u << 20) + 64);        // nz * 1.11 MB

    const size_t ubase = (4u << 20) + 64;
    const size_t pb16  = (size_t)16 * NTRI * 2048 * 4;   // 17.8 MB
    const int nz = (ws_size >= ubase + pb16) ? 16 : 8;   // ws_size const/session
    const int slice = HH / nz;

    proj_mfma_kernel<<<512, 256, 0, stream>>>(lm, W1, b1, Ea, Eb);
    pair_kernel<<<dim3(NTRI, nz), 256, 0, stream>>>(Ea, Eb, W2, pbuf, slice);
    combine_kernel<<<(NTRI * 2048) / 256, 256, 0, stream>>>(pbuf, W2, b2, out, nz);
}